// Round 1
// baseline (437.353 us; speedup 1.0000x reference)
//
#include <hip/hip_runtime.h>
#include <math.h>

#define TPB 512          // 8 waves/block; 1024 blocks -> 8 waves/SIMD (full occupancy)
#define NBLK 1024
#define CCLS 1000

// Wave-wide f32 sum via DPP (VALU pipe only, no DS/lgkmcnt):
// row_shr 1/2/4/8 -> lane15 of each 16-row holds row sum;
// row_bcast:15 (rows 1,3) and row_bcast:31 (rows 2,3) combine -> lane 63 = total.
// readlane(63) broadcasts through an SGPR. Chain = 6 VALU adds + 1 readlane.
__device__ __forceinline__ float wave_sum64(float x) {
  int t;
  t = __builtin_amdgcn_update_dpp(0, __float_as_int(x), 0x111, 0xf, 0xf, true); x += __int_as_float(t); // row_shr:1
  t = __builtin_amdgcn_update_dpp(0, __float_as_int(x), 0x112, 0xf, 0xf, true); x += __int_as_float(t); // row_shr:2
  t = __builtin_amdgcn_update_dpp(0, __float_as_int(x), 0x114, 0xf, 0xf, true); x += __int_as_float(t); // row_shr:4
  t = __builtin_amdgcn_update_dpp(0, __float_as_int(x), 0x118, 0xf, 0xf, true); x += __int_as_float(t); // row_shr:8
  t = __builtin_amdgcn_update_dpp(0, __float_as_int(x), 0x142, 0xa, 0xf, true); x += __int_as_float(t); // row_bcast:15 -> rows 1,3
  t = __builtin_amdgcn_update_dpp(0, __float_as_int(x), 0x143, 0xc, 0xf, true); x += __int_as_float(t); // row_bcast:31 -> rows 2,3
  return __int_as_float(__builtin_amdgcn_readlane(__float_as_int(x), 63));
}

// v_exp_f32 computes 2^x; fold log2e into the per-row scalar instead of per element.
__device__ __forceinline__ float fexp2(float x) {
#if __has_builtin(__builtin_amdgcn_exp2f)
  return __builtin_amdgcn_exp2f(x);
#else
  return exp2f(x);
#endif
}

// Agent-scope (device-coherent) load: safe across per-XCD L2s.
__device__ __forceinline__ float coherent_load(const float* p) {
  return __hip_atomic_load(p, __ATOMIC_RELAXED, __HIP_MEMORY_SCOPE_AGENT);
}

// Fully fused: per-row L2norm+softmax accumulate, bincount (as -1.0 into the same
// LDS accumulator -> g_acc holds sum(probs) - counts), and last-block epilogue.
//
// One row per wave per iteration: lane l owns float4 chunks {l, 64+l, 128+l, 192+l}
// (last valid if l<58). No max-subtraction: x*inv in [-1,1] after L2 norm ->
// exp in [0.37,2.72], softmax shift-invariant.
__global__ __launch_bounds__(TPB, 8) void mdca_fused(const float* __restrict__ X,
                                                     const int* __restrict__ tgt,
                                                     float* __restrict__ g_acc,
                                                     float* __restrict__ out, int B) {
  __shared__ float sacc[1024];
  __shared__ float s_r[TPB / 64];
  __shared__ int s_last;
  const int t = threadIdx.x;
  const int lane = t & 63;
  const int wid = blockIdx.x * (TPB / 64) + (t >> 6);
  const int nw = NBLK * (TPB / 64);   // 8192 waves -> 8 rows/wave
  const bool v3 = (lane < 58);

  for (int i = t; i < 1024; i += TPB) sacc[i] = 0.f;

  float acc[16];
  #pragma unroll
  for (int i = 0; i < 16; ++i) acc[i] = 0.f;

  const float4 Z = make_float4(0.f, 0.f, 0.f, 0.f);

  for (int r = wid; r < B; r += nw) {
    const float4* b = reinterpret_cast<const float4*>(X + (size_t)r * CCLS);
    float4 a0 = b[lane];
    float4 a1 = b[64 + lane];
    float4 a2 = b[128 + lane];
    float4 a3 = v3 ? b[192 + lane] : Z;

    float ss = a0.x*a0.x + a0.y*a0.y + a0.z*a0.z + a0.w*a0.w
             + a1.x*a1.x + a1.y*a1.y + a1.z*a1.z + a1.w*a1.w
             + a2.x*a2.x + a2.y*a2.y + a2.z*a2.z + a2.w*a2.w
             + a3.x*a3.x + a3.y*a3.y + a3.z*a3.z + a3.w*a3.w;
    ss = wave_sum64(ss);

    // scale by log2(e) once per row: exp(x*inv) == 2^(x*il2)
    const float il2 = 1.44269504f / (sqrtf(ss) + 1e-7f);

    a0.x=fexp2(a0.x*il2); a0.y=fexp2(a0.y*il2); a0.z=fexp2(a0.z*il2); a0.w=fexp2(a0.w*il2);
    a1.x=fexp2(a1.x*il2); a1.y=fexp2(a1.y*il2); a1.z=fexp2(a1.z*il2); a1.w=fexp2(a1.w*il2);
    a2.x=fexp2(a2.x*il2); a2.y=fexp2(a2.y*il2); a2.z=fexp2(a2.z*il2); a2.w=fexp2(a2.w*il2);
    a3.x=fexp2(a3.x*il2); a3.y=fexp2(a3.y*il2); a3.z=fexp2(a3.z*il2); a3.w=fexp2(a3.w*il2);
    if (!v3) a3 = Z;   // kill exp(0)=1 pollution from inactive chunk-3 lanes

    float es = a0.x+a0.y+a0.z+a0.w + a1.x+a1.y+a1.z+a1.w
             + a2.x+a2.y+a2.z+a2.w + a3.x+a3.y+a3.z+a3.w;
    es = wave_sum64(es);

    const float invS = 1.0f / es;

    acc[0]  += a0.x*invS;  acc[1]  += a0.y*invS;  acc[2]  += a0.z*invS;  acc[3]  += a0.w*invS;
    acc[4]  += a1.x*invS;  acc[5]  += a1.y*invS;  acc[6]  += a1.z*invS;  acc[7]  += a1.w*invS;
    acc[8]  += a2.x*invS;  acc[9]  += a2.y*invS;  acc[10] += a2.z*invS;  acc[11] += a2.w*invS;
    acc[12] += a3.x*invS;  acc[13] += a3.y*invS;  acc[14] += a3.z*invS;  acc[15] += a3.w*invS;
  }

  // combine 8 waves in LDS (sacc index == class)
  __syncthreads();   // also guarantees sacc zero-init is complete everywhere
  #pragma unroll
  for (int k = 0; k < 4; ++k)
    #pragma unroll
    for (int j = 0; j < 4; ++j)
      atomicAdd(&sacc[k * 256 + lane * 4 + j], acc[k * 4 + j]);

  // fused bincount: each block owns 64 consecutive targets per stride pass,
  // folded as -1.0 into the same per-class accumulator.
  if (t < 64) {
    for (int i = blockIdx.x * 64 + t; i < B; i += NBLK * 64)
      atomicAdd(&sacc[tgt[i]], -1.0f);
  }
  __syncthreads();

  // one global atomic per class per block: g_acc[c] = sum(probs) - counts
  #pragma unroll
  for (int j = 0; j < 2; ++j) {
    int c = t * 2 + j;
    if (c < CCLS) atomicAdd(&g_acc[c], sacc[c]);
  }

  // last-block-done epilogue. The __syncthreads barrier drains vmcnt(0) per wave,
  // so every global atomic of this block is complete before thread 0 signals.
  __syncthreads();
  if (t == 0) {
    __threadfence();
    unsigned* dcnt = (unsigned*)(g_acc + 1000);   // zeroed by the same memset
    unsigned old = __hip_atomic_fetch_add(dcnt, 1u, __ATOMIC_ACQ_REL,
                                          __HIP_MEMORY_SCOPE_AGENT);
    s_last = (old == (unsigned)(NBLK - 1));
  }
  __syncthreads();
  if (s_last) {
    const float invB = 1.0f / (float)B;
    float s = 0.f;
    for (int c = t; c < CCLS; c += TPB)
      s += fabsf(coherent_load(&g_acc[c]) * invB);
    s = wave_sum64(s);
    if (lane == 0) s_r[t >> 6] = s;
    __syncthreads();
    if (t == 0) {
      float tot = 0.f;
      #pragma unroll
      for (int w = 0; w < TPB / 64; ++w) tot += s_r[w];
      out[0] = tot / (float)CCLS;
    }
  }
}

extern "C" void kernel_launch(void* const* d_in, const int* in_sizes, int n_in,
                              void* d_out, int out_size, void* d_ws, size_t ws_size,
                              hipStream_t stream) {
  const float* X = (const float*)d_in[0];
  const int* tgt = (const int*)d_in[1];
  const int B = in_sizes[1];

  float* g_acc = (float*)d_ws;   // [1000] delta accumulator + [1] done-counter

  hipMemsetAsync(d_ws, 0, 1024 * sizeof(float), stream);
  mdca_fused<<<NBLK, TPB, 0, stream>>>(X, tgt, g_acc, (float*)d_out, B);
}

// Round 2
// 433.965 us; speedup vs baseline: 1.0078x; 1.0078x over previous
//
#include <hip/hip_runtime.h>
#include <math.h>

#define TPB 512          // 8 waves/block; 1024 blocks -> 32 waves/CU (full residency)
#define NBLK 1024
#define CCLS 1000
#define NPART 32         // partial accumulator arrays; contention per address = NBLK/NPART

// Wave-wide f32 sum via DPP (VALU pipe only, no DS/lgkmcnt):
// row_shr 1/2/4/8 -> lane15 of each 16-row holds row sum;
// row_bcast:15 (rows 1,3) and row_bcast:31 (rows 2,3) combine -> lane 63 = total.
// readlane(63) broadcasts through an SGPR. Chain = 6 VALU adds + 1 readlane.
__device__ __forceinline__ float wave_sum64(float x) {
  int t;
  t = __builtin_amdgcn_update_dpp(0, __float_as_int(x), 0x111, 0xf, 0xf, true); x += __int_as_float(t); // row_shr:1
  t = __builtin_amdgcn_update_dpp(0, __float_as_int(x), 0x112, 0xf, 0xf, true); x += __int_as_float(t); // row_shr:2
  t = __builtin_amdgcn_update_dpp(0, __float_as_int(x), 0x114, 0xf, 0xf, true); x += __int_as_float(t); // row_shr:4
  t = __builtin_amdgcn_update_dpp(0, __float_as_int(x), 0x118, 0xf, 0xf, true); x += __int_as_float(t); // row_shr:8
  t = __builtin_amdgcn_update_dpp(0, __float_as_int(x), 0x142, 0xa, 0xf, true); x += __int_as_float(t); // row_bcast:15 -> rows 1,3
  t = __builtin_amdgcn_update_dpp(0, __float_as_int(x), 0x143, 0xc, 0xf, true); x += __int_as_float(t); // row_bcast:31 -> rows 2,3
  return __int_as_float(__builtin_amdgcn_readlane(__float_as_int(x), 63));
}

// Agent-scope (device-coherent) load: safe across per-XCD L2s.
__device__ __forceinline__ float coherent_load(const float* p) {
  return __hip_atomic_load(p, __ATOMIC_RELAXED, __HIP_MEMORY_SCOPE_AGENT);
}

// Fully fused: per-row L2norm+softmax accumulate, bincount (as -1.0 into the same
// LDS accumulator -> partials hold sum(probs) - counts), and last-block epilogue.
//
// One row per wave per iteration: lane l owns float4 chunks {l, 64+l, 128+l, 192+l}
// (last valid if l<58). No max-subtraction: x*inv in [-1,1] after L2 norm ->
// exp in [0.37,2.72], softmax shift-invariant.
__global__ __launch_bounds__(TPB, 8) void mdca_fused(const float* __restrict__ X,
                                                     const int* __restrict__ tgt,
                                                     float* __restrict__ g_ws,
                                                     float* __restrict__ out, int B) {
  __shared__ float sacc[1024];
  __shared__ float s_r[TPB / 64];
  __shared__ int s_last;
  const int t = threadIdx.x;
  const int lane = t & 63;
  const int wid = blockIdx.x * (TPB / 64) + (t >> 6);
  const int nw = NBLK * (TPB / 64);   // 8192 waves -> 8 rows/wave
  const bool v3 = (lane < 58);

  for (int i = t; i < 1024; i += TPB) sacc[i] = 0.f;

  float acc[16];
  #pragma unroll
  for (int i = 0; i < 16; ++i) acc[i] = 0.f;

  const float4 Z = make_float4(0.f, 0.f, 0.f, 0.f);

  for (int r = wid; r < B; r += nw) {
    const float4* b = reinterpret_cast<const float4*>(X + (size_t)r * CCLS);
    float4 a0 = b[lane];
    float4 a1 = b[64 + lane];
    float4 a2 = b[128 + lane];
    float4 a3 = v3 ? b[192 + lane] : Z;

    float ss = a0.x*a0.x + a0.y*a0.y + a0.z*a0.z + a0.w*a0.w
             + a1.x*a1.x + a1.y*a1.y + a1.z*a1.z + a1.w*a1.w
             + a2.x*a2.x + a2.y*a2.y + a2.z*a2.z + a2.w*a2.w
             + a3.x*a3.x + a3.y*a3.y + a3.z*a3.z + a3.w*a3.w;
    ss = wave_sum64(ss);

    const float inv = 1.0f / (sqrtf(ss) + 1e-7f);

    // exp in place (__expf -> v_exp_f32 + mul; known-good codegen)
    a0.x=__expf(a0.x*inv); a0.y=__expf(a0.y*inv); a0.z=__expf(a0.z*inv); a0.w=__expf(a0.w*inv);
    a1.x=__expf(a1.x*inv); a1.y=__expf(a1.y*inv); a1.z=__expf(a1.z*inv); a1.w=__expf(a1.w*inv);
    a2.x=__expf(a2.x*inv); a2.y=__expf(a2.y*inv); a2.z=__expf(a2.z*inv); a2.w=__expf(a2.w*inv);
    a3.x=__expf(a3.x*inv); a3.y=__expf(a3.y*inv); a3.z=__expf(a3.z*inv); a3.w=__expf(a3.w*inv);
    if (!v3) a3 = Z;   // kill exp(0)=1 pollution from inactive chunk-3 lanes

    float es = a0.x+a0.y+a0.z+a0.w + a1.x+a1.y+a1.z+a1.w
             + a2.x+a2.y+a2.z+a2.w + a3.x+a3.y+a3.z+a3.w;
    es = wave_sum64(es);

    const float invS = 1.0f / es;

    acc[0]  += a0.x*invS;  acc[1]  += a0.y*invS;  acc[2]  += a0.z*invS;  acc[3]  += a0.w*invS;
    acc[4]  += a1.x*invS;  acc[5]  += a1.y*invS;  acc[6]  += a1.z*invS;  acc[7]  += a1.w*invS;
    acc[8]  += a2.x*invS;  acc[9]  += a2.y*invS;  acc[10] += a2.z*invS;  acc[11] += a2.w*invS;
    acc[12] += a3.x*invS;  acc[13] += a3.y*invS;  acc[14] += a3.z*invS;  acc[15] += a3.w*invS;
  }

  // combine 8 waves in LDS (sacc index == class)
  __syncthreads();   // also guarantees sacc zero-init is complete everywhere
  #pragma unroll
  for (int k = 0; k < 4; ++k)
    #pragma unroll
    for (int j = 0; j < 4; ++j)
      atomicAdd(&sacc[k * 256 + lane * 4 + j], acc[k * 4 + j]);

  // fused bincount: each block owns 64 consecutive targets per stride pass,
  // folded as -1.0 into the same per-class accumulator.
  if (t < 64) {
    for (int i = blockIdx.x * 64 + t; i < B; i += NBLK * 64)
      atomicAdd(&sacc[tgt[i]], -1.0f);
  }
  __syncthreads();

  // Scatter into NPART partial arrays: per-address contention = NBLK/NPART = 32
  // (vs 1024 on a single array -> the invisible-stall fix). Blocks sharing a
  // partition are congruent mod 32, hence on the SAME XCD (b%8 fixed) -> L2-local.
  float* part = g_ws + (size_t)(blockIdx.x & (NPART - 1)) * 1024;
  #pragma unroll
  for (int j = 0; j < 2; ++j) {
    int c = t * 2 + j;
    if (c < CCLS) atomicAdd(&part[c], sacc[c]);
  }

  // last-block-done epilogue. __syncthreads drains vmcnt(0) per wave, so every
  // global atomic of this block is complete before thread 0 signals.
  __syncthreads();
  if (t == 0) {
    __threadfence();
    unsigned* dcnt = (unsigned*)(g_ws + NPART * 1024);   // own cache line, zeroed by memset
    unsigned old = __hip_atomic_fetch_add(dcnt, 1u, __ATOMIC_ACQ_REL,
                                          __HIP_MEMORY_SCOPE_AGENT);
    s_last = (old == (unsigned)(NBLK - 1));
  }
  __syncthreads();
  if (s_last) {
    const float invB = 1.0f / (float)B;
    float s = 0.f;
    for (int c = t; c < CCLS; c += TPB) {
      float v = 0.f;
      #pragma unroll
      for (int k = 0; k < NPART; ++k)
        v += coherent_load(&g_ws[k * 1024 + c]);
      s += fabsf(v * invB);
    }
    s = wave_sum64(s);
    if (lane == 0) s_r[t >> 6] = s;
    __syncthreads();
    if (t == 0) {
      float tot = 0.f;
      #pragma unroll
      for (int w = 0; w < TPB / 64; ++w) tot += s_r[w];
      out[0] = tot / (float)CCLS;
    }
  }
}

extern "C" void kernel_launch(void* const* d_in, const int* in_sizes, int n_in,
                              void* d_out, int out_size, void* d_ws, size_t ws_size,
                              hipStream_t stream) {
  const float* X = (const float*)d_in[0];
  const int* tgt = (const int*)d_in[1];
  const int B = in_sizes[1];

  float* g_ws = (float*)d_ws;   // [NPART*1024] partials + [1] done-counter

  hipMemsetAsync(d_ws, 0, (NPART * 1024 + 64) * sizeof(float), stream);
  mdca_fused<<<NBLK, TPB, 0, stream>>>(X, tgt, g_ws, (float*)d_out, B);
}

// Round 3
// 380.178 us; speedup vs baseline: 1.1504x; 1.1415x over previous
//
#include <hip/hip_runtime.h>
#include <math.h>

#define TPB 512          // 8 waves/block; 1024 blocks -> 32 waves/CU (full residency)
#define NBLK 1024
#define CCLS 1000

// Wave-wide f32 sum via DPP (VALU pipe only, no DS/lgkmcnt):
// row_shr 1/2/4/8 -> lane15 of each 16-row holds row sum;
// row_bcast:15 (rows 1,3) and row_bcast:31 (rows 2,3) combine -> lane 63 = total.
// readlane(63) broadcasts through an SGPR. Chain = 6 VALU adds + 1 readlane.
__device__ __forceinline__ float wave_sum64(float x) {
  int t;
  t = __builtin_amdgcn_update_dpp(0, __float_as_int(x), 0x111, 0xf, 0xf, true); x += __int_as_float(t); // row_shr:1
  t = __builtin_amdgcn_update_dpp(0, __float_as_int(x), 0x112, 0xf, 0xf, true); x += __int_as_float(t); // row_shr:2
  t = __builtin_amdgcn_update_dpp(0, __float_as_int(x), 0x114, 0xf, 0xf, true); x += __int_as_float(t); // row_shr:4
  t = __builtin_amdgcn_update_dpp(0, __float_as_int(x), 0x118, 0xf, 0xf, true); x += __int_as_float(t); // row_shr:8
  t = __builtin_amdgcn_update_dpp(0, __float_as_int(x), 0x142, 0xa, 0xf, true); x += __int_as_float(t); // row_bcast:15 -> rows 1,3
  t = __builtin_amdgcn_update_dpp(0, __float_as_int(x), 0x143, 0xc, 0xf, true); x += __int_as_float(t); // row_bcast:31 -> rows 2,3
  return __int_as_float(__builtin_amdgcn_readlane(__float_as_int(x), 63));
}

// Stage 1: per-row L2norm + softmax accumulate + fused bincount (-1.0 into the
// same per-class LDS accumulator), then PLAIN stores of the block's 1000 partials
// into a private workspace slice. ZERO global atomics (the r1/r2 1M-atomic storm
// was the invisible 150us: duration was data-source-independent, VALU ~10%,
// and insensitive to contention partitioning -> RMW *count* limited).
//
// One row per wave per iteration: lane l owns float4 chunks {l, 64+l, 128+l, 192+l}
// (last valid if l<58). No max-subtraction: x*inv in [-1,1] after L2 norm ->
// exp in [0.37,2.72], softmax shift-invariant.
__global__ __launch_bounds__(TPB, 8) void mdca_main(const float* __restrict__ X,
                                                    const int* __restrict__ tgt,
                                                    float* __restrict__ part, int B) {
  __shared__ float sacc[1024];
  const int t = threadIdx.x;
  const int lane = t & 63;
  const int wid = blockIdx.x * (TPB / 64) + (t >> 6);
  const int nw = NBLK * (TPB / 64);   // 8192 waves -> 8 rows/wave
  const bool v3 = (lane < 58);

  for (int i = t; i < 1024; i += TPB) sacc[i] = 0.f;

  float acc[16];
  #pragma unroll
  for (int i = 0; i < 16; ++i) acc[i] = 0.f;

  const float4 Z = make_float4(0.f, 0.f, 0.f, 0.f);

  for (int r = wid; r < B; r += nw) {
    const float4* b = reinterpret_cast<const float4*>(X + (size_t)r * CCLS);
    float4 a0 = b[lane];
    float4 a1 = b[64 + lane];
    float4 a2 = b[128 + lane];
    float4 a3 = v3 ? b[192 + lane] : Z;

    float ss = a0.x*a0.x + a0.y*a0.y + a0.z*a0.z + a0.w*a0.w
             + a1.x*a1.x + a1.y*a1.y + a1.z*a1.z + a1.w*a1.w
             + a2.x*a2.x + a2.y*a2.y + a2.z*a2.z + a2.w*a2.w
             + a3.x*a3.x + a3.y*a3.y + a3.z*a3.z + a3.w*a3.w;
    ss = wave_sum64(ss);

    const float inv = 1.0f / (sqrtf(ss) + 1e-7f);

    // exp in place (__expf -> v_exp_f32 + mul; known-good codegen)
    a0.x=__expf(a0.x*inv); a0.y=__expf(a0.y*inv); a0.z=__expf(a0.z*inv); a0.w=__expf(a0.w*inv);
    a1.x=__expf(a1.x*inv); a1.y=__expf(a1.y*inv); a1.z=__expf(a1.z*inv); a1.w=__expf(a1.w*inv);
    a2.x=__expf(a2.x*inv); a2.y=__expf(a2.y*inv); a2.z=__expf(a2.z*inv); a2.w=__expf(a2.w*inv);
    a3.x=__expf(a3.x*inv); a3.y=__expf(a3.y*inv); a3.z=__expf(a3.z*inv); a3.w=__expf(a3.w*inv);
    if (!v3) a3 = Z;   // kill exp(0)=1 pollution from inactive chunk-3 lanes

    float es = a0.x+a0.y+a0.z+a0.w + a1.x+a1.y+a1.z+a1.w
             + a2.x+a2.y+a2.z+a2.w + a3.x+a3.y+a3.z+a3.w;
    es = wave_sum64(es);

    const float invS = 1.0f / es;

    acc[0]  += a0.x*invS;  acc[1]  += a0.y*invS;  acc[2]  += a0.z*invS;  acc[3]  += a0.w*invS;
    acc[4]  += a1.x*invS;  acc[5]  += a1.y*invS;  acc[6]  += a1.z*invS;  acc[7]  += a1.w*invS;
    acc[8]  += a2.x*invS;  acc[9]  += a2.y*invS;  acc[10] += a2.z*invS;  acc[11] += a2.w*invS;
    acc[12] += a3.x*invS;  acc[13] += a3.y*invS;  acc[14] += a3.z*invS;  acc[15] += a3.w*invS;
  }

  // combine 8 waves in LDS (sacc index == class)
  __syncthreads();   // also guarantees sacc zero-init is complete everywhere
  #pragma unroll
  for (int k = 0; k < 4; ++k)
    #pragma unroll
    for (int j = 0; j < 4; ++j)
      atomicAdd(&sacc[k * 256 + lane * 4 + j], acc[k * 4 + j]);

  // fused bincount: each block owns 64 consecutive targets per stride pass,
  // folded as -1.0 into the same per-class accumulator.
  if (t < 64) {
    for (int i = blockIdx.x * 64 + t; i < B; i += NBLK * 64)
      atomicAdd(&sacc[tgt[i]], -1.0f);
  }
  __syncthreads();

  // plain coalesced stores into this block's private slice -- no atomics, no
  // zero-init needed; cross-XCD visibility via the kernel dispatch boundary.
  float* my = part + (size_t)blockIdx.x * 1024;
  #pragma unroll
  for (int j = 0; j < 2; ++j) {
    int c = t * 2 + j;
    if (c < CCLS) my[c] = sacc[c];
  }
}

// Stage 2: column-reduce the 1024 block-partials, |.|, mean.
// Block b owns classes [4b, 4b+4); thread t float4-sums k = t, t+256, t+512, t+768.
// 250 blocks x 16KB useful (64KB fetched) ~ L2/L3 speed, a few us.
__global__ __launch_bounds__(256) void mdca_reduce(const float* __restrict__ part,
                                                   float* __restrict__ out, int B) {
  __shared__ float4 sred[4];
  const int t = threadIdx.x;
  const float* p = part + 4 * blockIdx.x;

  float4 s = make_float4(0.f, 0.f, 0.f, 0.f);
  #pragma unroll
  for (int j = 0; j < 4; ++j) {
    const float4 v = *reinterpret_cast<const float4*>(p + (size_t)(t + 256 * j) * 1024);
    s.x += v.x; s.y += v.y; s.z += v.z; s.w += v.w;
  }
  s.x = wave_sum64(s.x);
  s.y = wave_sum64(s.y);
  s.z = wave_sum64(s.z);
  s.w = wave_sum64(s.w);
  if ((t & 63) == 0) sred[t >> 6] = s;
  __syncthreads();
  if (t == 0) {
    float4 a = sred[0];
    #pragma unroll
    for (int w = 1; w < 4; ++w) {
      a.x += sred[w].x; a.y += sred[w].y; a.z += sred[w].z; a.w += sred[w].w;
    }
    const float invB = 1.0f / (float)B;
    float r = fabsf(a.x * invB) + fabsf(a.y * invB)
            + fabsf(a.z * invB) + fabsf(a.w * invB);
    atomicAdd(out, r / (float)CCLS);   // 250 adds total, zeroed by memset
  }
}

extern "C" void kernel_launch(void* const* d_in, const int* in_sizes, int n_in,
                              void* d_out, int out_size, void* d_ws, size_t ws_size,
                              hipStream_t stream) {
  const float* X = (const float*)d_in[0];
  const int* tgt = (const int*)d_in[1];
  const int B = in_sizes[1];

  float* part = (float*)d_ws;   // [NBLK * 1024] block-partial arrays (fully overwritten)

  hipMemsetAsync(d_out, 0, sizeof(float), stream);
  mdca_main<<<NBLK, TPB, 0, stream>>>(X, tgt, part, B);
  mdca_reduce<<<250, 256, 0, stream>>>(part, (float*)d_out, B);
}